// Round 6
// baseline (344.338 us; speedup 1.0000x reference)
//
#include <hip/hip_runtime.h>
#include <stdint.h>

#define DIMC 256
#define RTOT 1024
#define NE 64
#define NSLOT 1024
#define RCN 8      // r-chunks (grid.y)
#define RCW 128    // r-columns per chunk
#define TILE 32    // slots per pass (2 MFMA m-tiles)
#define XSTR 264   // padded LDS row stride for A-operand (bf16 elems)

typedef short bfrag __attribute__((ext_vector_type(8)));
typedef float f32x4 __attribute__((ext_vector_type(4)));

#define WAITV(n) asm volatile("s_waitcnt vmcnt(" #n ")" ::: "memory")
#define LGKM0()  asm volatile("s_waitcnt lgkmcnt(0)" ::: "memory")
#define LGKM0_BAR()                                          \
  do {                                                       \
    LGKM0();                                                 \
    __builtin_amdgcn_s_barrier();                            \
  } while (0)

static __device__ __forceinline__ unsigned short f2bf(float f) {
  unsigned u = __float_as_uint(f);  // RNE
  return (unsigned short)((u + 0x7FFFu + ((u >> 16) & 1u)) >> 16);
}

static __device__ __forceinline__ bfrag pack8(const float* f) {
  union { unsigned short u[8]; bfrag v; } r;
#pragma unroll
  for (int i = 0; i < 8; ++i) r.u[i] = f2bf(f[i]);
  return r.v;
}

static __device__ __forceinline__ void gload16(const float* g, float* l) {
  __builtin_amdgcn_global_load_lds(
      (const __attribute__((address_space(1))) void*)g,
      (__attribute__((address_space(3))) void*)l, 16, 0, 0);
}

// ---------------- fused bucket + 2-layer MLP + last-block reduce ------------
// R6: counters say effective clock ~0.4-0.5 GHz for these short-duty kernels
// (VALUBusy 7% over 55us vs ~2k VALU-cy/SIMD of real work) -> minimize path
// CYCLES, block rounds, and dispatches; bytes don't matter.
//  * WB = 6KB/wave 3-slot ring (2KB granules), per-wave counted vmcnt,
//    zero barriers inside the weight streams. LDS 66.6KB -> 2 blocks/CU:
//    all 512 blocks co-resident in ONE round.
//  * L2 loads issued before the h-park barriers (latency hidden under them).
//  * reduce fused: per-expert done-counter in ws; the 8th rc-block to finish
//    sums the 8 partial planes + b2 and writes out (out written exactly once
//    -> no 1MB memset, no reduce dispatch). Only a 256B memset remains.
// C/D: col=lane&15, row=(lane>>4)*4+reg.
template <int USE_WS>
__global__ __launch_bounds__(512, 4) void mlp_kernel(
    const float* __restrict__ slots, const float* __restrict__ w1,
    const float* __restrict__ b1, const float* __restrict__ w2,
    const float* __restrict__ b2, const int* __restrict__ indices,
    float* __restrict__ part, int* __restrict__ done,
    float* __restrict__ out) {
  const int e  = blockIdx.x;   // 0..63  (fast dim -> XCD id = e%8)
  const int rc = blockIdx.y;   // 0..7
  const int t  = threadIdx.x;
  const int l  = t & 63;       // lane
  const int w  = t >> 6;       // wave 0..7
  const int ln = l & 15;       // fragment n/m index
  const int kg = l >> 4;       // k-group 0..3
  const int rbase = rc * RCW;

  __shared__ __align__(16) float WB[8][1536];              // 48 KB: 6KB/wave
  __shared__ __align__(16) unsigned short X[TILE * XSTR];  // 16.9 KB
  __shared__ unsigned short blist[NSLOT];                  // 2 KB
  __shared__ int sid[TILE];
  __shared__ int bn_s;
  __shared__ int lastf;

  // ---- in-block bucketing ----
  if (t == 0) bn_s = 0;
  __syncthreads();
  {
    int i0 = indices[t] & (NE - 1);
    int i1 = indices[t + 512] & (NE - 1);
    if (i0 == e) { int p = atomicAdd(&bn_s, 1); blist[p] = (unsigned short)t; }
    if (i1 == e) { int p = atomicAdd(&bn_s, 1); blist[p] = (unsigned short)(t + 512); }
  }
  __syncthreads();
  const int n = bn_s;
  if (n == 0) return;  // uniform per block; no outputs exist for this e

  const float* w1e = w1 + (size_t)e * DIMC * RTOT + rbase;                 // [d][r]
  const float* w2e = w2 + (size_t)e * RTOT * DIMC + (size_t)rbase * DIMC;  // [r][dout]
  const int   c    = w * 16 + ln;            // wave-local L1 column 0..127
  const float b1v  = b1[e * RTOT + rbase + c];
  float* WBw = WB[w];
  float* prc = part + (size_t)rc * NSLOT * DIMC;

  // L1 granule g (0..7) = k-rows [g*32,g*32+32) x wave's 16 cols = 2KB,
  // ring slot g%3. 2 gload16 (16 rows x 16 cols each).
  auto STG1 = [&](int g) {
#pragma unroll
    for (int q = 0; q < 2; ++q)
      gload16(w1e + (size_t)(g * 32 + q * 16 + (l >> 2)) * RTOT +
                  w * 16 + (l & 3) * 4,
              WBw + (g % 3) * 512 + q * 256 + l * 4);
  };
  // L2 sub-granule u (0..7) = r-rows [u*16,u*16+16) x wave's 32 cols = 2KB,
  // ring slot u%3. 2 gload16 (8 rows x 32 cols each).
  auto STG2 = [&](int u) {
#pragma unroll
    for (int q = 0; q < 2; ++q)
      gload16(w2e + (size_t)(u * 16 + q * 8 + (l >> 3)) * DIMC +
                  w * 32 + (l & 7) * 4,
              WBw + (u % 3) * 512 + q * 256 + l * 4);
  };

  for (int s0 = 0; s0 < n; s0 += TILE) {
    const int m = (n - s0 < TILE) ? (n - s0) : TILE;

    __syncthreads();  // prev pass fully done (drains stores: vmcnt(0) here)
    if (t < TILE) sid[t] = (t < m) ? (int)blist[s0 + t] : 0;
    __syncthreads();

    // ---- stage x tile: fp32 global -> bf16 LDS [slot][d]; zero pad rows
#pragma unroll
    for (int i = t; i < TILE * 64; i += 512) {
      int s = i >> 6, d4 = (i & 63) * 4;
      float4 v = make_float4(0.f, 0.f, 0.f, 0.f);
      if (s < m) v = ((const float4*)slots)[(size_t)sid[s] * 64 + (i & 63)];
      union { unsigned short u[4]; uint2 q; } p;
      p.u[0] = f2bf(v.x); p.u[1] = f2bf(v.y);
      p.u[2] = f2bf(v.z); p.u[3] = f2bf(v.w);
      *(uint2*)&X[s * XSTR + d4] = p.q;
    }
    __syncthreads();  // x visible; vmcnt==0 (compiler drains at barrier)

    // ==== layer 1: per-wave paced ring, no barriers ====
    f32x4 acc1[2];
    acc1[0] = (f32x4)(0.f); acc1[1] = (f32x4)(0.f);
    STG1(0); STG1(1); STG1(2);

#define CONS1(ks)                                                           \
  {                                                                         \
    const float* base = WBw + ((ks) % 3) * 512;                             \
    float f[8];                                                             \
    _Pragma("unroll") for (int j = 0; j < 8; ++j)                           \
        f[j] = base[(kg * 8 + j) * 16 + ln];                                \
    bfrag b = pack8(f);                                                     \
    bfrag a0 = *(const bfrag*)&X[ln * XSTR + (ks) * 32 + kg * 8];           \
    bfrag a1 = *(const bfrag*)&X[(16 + ln) * XSTR + (ks) * 32 + kg * 8];    \
    acc1[0] = __builtin_amdgcn_mfma_f32_16x16x32_bf16(a0, b, acc1[0], 0, 0, 0); \
    acc1[1] = __builtin_amdgcn_mfma_f32_16x16x32_bf16(a1, b, acc1[1], 0, 0, 0); \
  }

    WAITV(4); CONS1(0); LGKM0(); STG1(3);
    WAITV(4); CONS1(1); LGKM0(); STG1(4);
    WAITV(4); CONS1(2); LGKM0(); STG1(5);
    WAITV(4); CONS1(3); LGKM0(); STG1(6);
    WAITV(4); CONS1(4); LGKM0(); STG1(7);
    WAITV(4); CONS1(5);
    WAITV(2); CONS1(6);
    WAITV(0); CONS1(7);
#undef CONS1

    // ==== issue first L2 sub-granules; latency hides under the barriers ====
    LGKM0();  // L1 ds_reads retired before slot reuse
    STG2(0); STG2(1); STG2(2);

    LGKM0_BAR();  // all waves done reading x from X (vmcnt NOT drained)

    // ---- bias + relu, park h (bf16) into X[slot][r_local 0..127]
#pragma unroll
    for (int mt = 0; mt < 2; ++mt)
#pragma unroll
      for (int reg = 0; reg < 4; ++reg) {
        float h = fmaxf(acc1[mt][reg] + b1v, 0.f);
        X[(mt * 16 + kg * 4 + reg) * XSTR + c] = f2bf(h);
      }
    LGKM0_BAR();  // parked h visible

    // ==== layer 2: per-wave paced; rt uses sub-granules u=2rt,2rt+1 ====
    f32x4 acc2[2][2];
#pragma unroll
    for (int mt = 0; mt < 2; ++mt)
#pragma unroll
      for (int nt = 0; nt < 2; ++nt) acc2[mt][nt] = (f32x4)(0.f);

#define CONS2(rt)                                                           \
  {                                                                         \
    const float* base = WBw + ((rt * 2 + (kg >> 1)) % 3) * 512 +            \
                        (kg & 1) * 256 + ln;                                \
    bfrag a0 = *(const bfrag*)&X[ln * XSTR + (rt) * 32 + kg * 8];           \
    bfrag a1 = *(const bfrag*)&X[(16 + ln) * XSTR + (rt) * 32 + kg * 8];    \
    _Pragma("unroll") for (int nt = 0; nt < 2; ++nt) {                      \
      float f[8];                                                           \
      _Pragma("unroll") for (int j = 0; j < 8; ++j)                         \
          f[j] = base[j * 32 + nt * 16];                                    \
      bfrag b = pack8(f);                                                   \
      acc2[0][nt] = __builtin_amdgcn_mfma_f32_16x16x32_bf16(a0, b, acc2[0][nt], 0, 0, 0); \
      acc2[1][nt] = __builtin_amdgcn_mfma_f32_16x16x32_bf16(a1, b, acc2[1][nt], 0, 0, 0); \
    }                                                                       \
  }

    WAITV(2); CONS2(0); LGKM0(); STG2(3); STG2(4);
    WAITV(2); CONS2(1); LGKM0(); STG2(5); STG2(6);
    WAITV(2); CONS2(2); LGKM0(); STG2(7);
    WAITV(0); CONS2(3);
#undef CONS2

    // ---- epilogue: partial plane (USE_WS) or atomic fallback
#pragma unroll
    for (int nt = 0; nt < 2; ++nt) {
      const int col = w * 32 + nt * 16 + ln;
      const float b2v = (!USE_WS && rc == 0) ? b2[e * DIMC + col] : 0.f;
#pragma unroll
      for (int mt = 0; mt < 2; ++mt)
#pragma unroll
        for (int reg = 0; reg < 4; ++reg) {
          const int row = mt * 16 + kg * 4 + reg;
          if (row < m) {
            if (USE_WS) {
              prc[(size_t)sid[row] * DIMC + col] = acc2[mt][nt][reg];
            } else {
              atomicAdd(&out[(size_t)sid[row] * DIMC + col],
                        acc2[mt][nt][reg] + b2v);
            }
          }
        }
    }
  }

  // ==== fused reduce: last rc-block per expert sums 8 planes + b2 ====
  if (USE_WS) {
    __threadfence();  // release partial stores
    if (t == 0) lastf = (atomicAdd(&done[e], 1) == RCN - 1);
    __syncthreads();
    if (lastf) {
      __threadfence();  // acquire other blocks' partials
      for (int i = t; i < n * 64; i += 512) {
        const int s  = blist[i >> 6];
        const int c4 = i & 63;
        f32x4 acc = *(const f32x4*)(b2 + e * DIMC + c4 * 4);
#pragma unroll
        for (int r2 = 0; r2 < RCN; ++r2)
          acc += *(const f32x4*)(part + (size_t)r2 * NSLOT * DIMC +
                                 (size_t)s * DIMC + c4 * 4);
        *(f32x4*)(out + (size_t)s * DIMC + c4 * 4) = acc;
      }
    }
  }
}

extern "C" void kernel_launch(void* const* d_in, const int* in_sizes, int n_in,
                              void* d_out, int out_size, void* d_ws, size_t ws_size,
                              hipStream_t stream) {
  const float* slots   = (const float*)d_in[0];
  const float* w1      = (const float*)d_in[1];
  const float* b1      = (const float*)d_in[2];
  const float* w2      = (const float*)d_in[3];
  const float* b2      = (const float*)d_in[4];
  const int*   indices = (const int*)d_in[5];
  float* out = (float*)d_out;

  const size_t part_bytes = (size_t)RCN * NSLOT * DIMC * sizeof(float);  // 8 MB
  const size_t need = part_bytes + 256;
  if (ws_size >= need) {
    float* part = (float*)d_ws;
    int*   done = (int*)((char*)d_ws + part_bytes);
    hipMemsetAsync(done, 0, NE * sizeof(int), stream);  // 256 B
    mlp_kernel<1><<<dim3(NE, RCN), 512, 0, stream>>>(slots, w1, b1, w2, b2,
                                                     indices, part, done, out);
  } else {
    hipMemsetAsync(d_out, 0, (size_t)out_size * sizeof(float), stream);
    mlp_kernel<0><<<dim3(NE, RCN), 512, 0, stream>>>(slots, w1, b1, w2, b2,
                                                     indices, nullptr, nullptr,
                                                     out);
  }
}

// Round 7
// 296.549 us; speedup vs baseline: 1.1612x; 1.1612x over previous
//
#include <hip/hip_runtime.h>
#include <stdint.h>

#define DIMC 256
#define RTOT 1024
#define NE 64
#define NSLOT 1024
#define RCN 8      // r-chunks (grid.y)
#define RCW 128    // r-columns per chunk
#define TILE 32    // max slots per pass (2 MFMA m-tiles)
#define XSTR 264   // padded LDS row stride for A-operand (bf16 elems)
#define NT 16      // 16-tile weight stream: tiles 0..7 = W1, 8..15 = W2

typedef short bfrag __attribute__((ext_vector_type(8)));
typedef float f32x4 __attribute__((ext_vector_type(4)));

#define VMCNT(N) asm volatile("s_waitcnt vmcnt(" #N ")" ::: "memory")
#define LGKM0_BAR()                                          \
  do {                                                       \
    asm volatile("s_waitcnt lgkmcnt(0)" ::: "memory");       \
    __builtin_amdgcn_s_barrier();                            \
  } while (0)

static __device__ __forceinline__ unsigned short f2bf(float f) {
  unsigned u = __float_as_uint(f);  // RNE
  return (unsigned short)((u + 0x7FFFu + ((u >> 16) & 1u)) >> 16);
}

static __device__ __forceinline__ bfrag pack8(const float* f) {
  union { unsigned short u[8]; bfrag v; } r;
#pragma unroll
  for (int i = 0; i < 8; ++i) r.u[i] = f2bf(f[i]);
  return r.v;
}

static __device__ __forceinline__ void gload16(const float* g, float* l) {
  __builtin_amdgcn_global_load_lds(
      (const __attribute__((address_space(1))) void*)g,
      (__attribute__((address_space(3))) void*)l, 16, 0, 0);
}

// ------- fused bucket + 2-layer MLP + last-block reduce (R4 main loop) ------
// R4's 16-tile WT-ring main loop verbatim (proven 50us = fetch floor at the
// platform's ~1.5TB/s effective BW). New vs R4:
//  * STAGE(0)/STAGE(1) hoisted BEFORE the x-staging: tile-0/1 HBM latency
//    hides under the x-phase (in-order vmcnt retirement means the x-loop's
//    final consumption drains them -- by then they're long complete).
//  * reduce FUSED: per-expert done counter in ws, mod-8 test (poison-proof:
//    exactly 8 increments/expert/iteration -> exactly one block sees old%8==7
//    regardless of the counter's initial garbage -> NO memset node). Last
//    rc-block per expert sums the 8 partial planes + b2, writes out exactly
//    once (no 1MB out-memset either). R6's fence protocol (passed refcheck).
//  * single kernel node in the graph.
// C/D: col=lane&15, row=(lane>>4)*4+reg.
template <int USE_WS>
__global__ __launch_bounds__(512, 4) void mlp_kernel(
    const float* __restrict__ slots, const float* __restrict__ w1,
    const float* __restrict__ b1, const float* __restrict__ w2,
    const float* __restrict__ b2, const int* __restrict__ indices,
    float* __restrict__ part, int* __restrict__ done,
    float* __restrict__ out) {
  const int e  = blockIdx.x;   // 0..63  (fast dim -> XCD id = e%8)
  const int rc = blockIdx.y;   // 0..7
  const int t  = threadIdx.x;
  const int l  = t & 63;       // lane
  const int w  = t >> 6;       // wave 0..7
  const int ln = l & 15;       // fragment n/m index
  const int kg = l >> 4;       // k-group 0..3
  const int rbase = rc * RCW;

  __shared__ __align__(16) float WT[3][4096];              // 48 KB tile ring
  __shared__ __align__(16) unsigned short X[TILE * XSTR];  // 16.5 KB A-operand
  __shared__ unsigned short blist[NSLOT];                  // 2 KB
  __shared__ int sid[TILE];
  __shared__ int bn_s;
  __shared__ int lastf;

  // ---- in-block bucketing ----
  if (t == 0) bn_s = 0;
  __syncthreads();
  {
    int i0 = indices[t] & (NE - 1);
    int i1 = indices[t + 512] & (NE - 1);
    if (i0 == e) { int p = atomicAdd(&bn_s, 1); blist[p] = (unsigned short)t; }
    if (i1 == e) { int p = atomicAdd(&bn_s, 1); blist[p] = (unsigned short)(t + 512); }
  }
  __syncthreads();
  const int n = bn_s;
  if (n == 0) return;  // all 8 rc-blocks of e skip together -> mod-8 intact

  const float* w1e = w1 + (size_t)e * DIMC * RTOT + rbase;                 // [d][r]
  const float* w2e = w2 + (size_t)e * RTOT * DIMC + (size_t)rbase * DIMC;  // [r][dout]
  const int   c    = w * 16 + ln;            // wave-local column 0..127
  const float b1v  = b1[e * RTOT + rbase + c];
  float* prc = part + (size_t)rc * NSLOT * DIMC;

  auto STAGE = [&](int tt, float* buf) {
    if (tt < 8) {
      const float* g = w1e + (size_t)(tt * 32 + (t >> 5)) * RTOT + (t & 31) * 4;
      gload16(g, buf + t * 4);
      gload16(g + (size_t)16 * RTOT, buf + 2048 + t * 4);
    } else {
      const int rt = (tt - 8) >> 1, dh = tt & 1;
      const float* g =
          w2e + (size_t)(rt * 32 + (t >> 5)) * DIMC + dh * 128 + (t & 31) * 4;
      gload16(g, buf + t * 4);
      gload16(g + 16 * DIMC, buf + 2048 + t * 4);
    }
  };

  for (int s0 = 0; s0 < n; s0 += TILE) {
    const int m = (n - s0 < TILE) ? (n - s0) : TILE;

    LGKM0_BAR();  // previous pass fully done
    if (t < TILE) sid[t] = (t < m) ? (int)blist[s0 + t] : 0;
    LGKM0_BAR();  // sid visible

    // ---- hoisted prologue stages: latency hides under the x-phase
    STAGE(0, WT[0]);
    STAGE(1, WT[1]);

    // ---- stage x tile: fp32 global -> bf16 LDS [slot][d]; zero pad rows
#pragma unroll
    for (int i = t; i < TILE * 64; i += 512) {
      int s = i >> 6, d4 = (i & 63) * 4;
      float4 v = make_float4(0.f, 0.f, 0.f, 0.f);
      if (s < m) v = ((const float4*)slots)[(size_t)sid[s] * 64 + (i & 63)];
      union { unsigned short u[4]; uint2 q; } p;
      p.u[0] = f2bf(v.x); p.u[1] = f2bf(v.y);
      p.u[2] = f2bf(v.z); p.u[3] = f2bf(v.w);
      *(uint2*)&X[s * XSTR + d4] = p.q;
    }

    f32x4 acc1[2];
    acc1[0] = (f32x4)(0.f); acc1[1] = (f32x4)(0.f);
    f32x4 acc2[2][2];
#pragma unroll
    for (int mt = 0; mt < 2; ++mt)
#pragma unroll
      for (int dh = 0; dh < 2; ++dh) acc2[mt][dh] = (f32x4)(0.f);

#pragma unroll
    for (int tt = 0; tt < NT; ++tt) {
      if (tt < NT - 1) VMCNT(2);
      else             VMCNT(0);
      LGKM0_BAR();  // tile tt landed, compute tt-1 done, X visible

      if (tt == 8) {
        // park h = relu(acc1 + b1) into X[slot][r_local]
#pragma unroll
        for (int mt = 0; mt < 2; ++mt)
#pragma unroll
          for (int reg = 0; reg < 4; ++reg) {
            float h = fmaxf(acc1[mt][reg] + b1v, 0.f);
            X[(mt * 16 + kg * 4 + reg) * XSTR + c] = f2bf(h);
          }
        LGKM0_BAR();  // parked h visible
      }

      if (tt + 2 < NT) STAGE(tt + 2, WT[(tt + 2) % 3]);

      {
        const float* buf = WT[tt % 3];
        float f[8];
#pragma unroll
        for (int j = 0; j < 8; ++j) f[j] = buf[(kg * 8 + j) * RCW + c];
        bfrag b = pack8(f);
        if (tt < 8) {  // layer 1, K-step tt
          bfrag a0 = *(const bfrag*)&X[ln * XSTR + tt * 32 + kg * 8];
          bfrag a1 = *(const bfrag*)&X[(16 + ln) * XSTR + tt * 32 + kg * 8];
          acc1[0] = __builtin_amdgcn_mfma_f32_16x16x32_bf16(a0, b, acc1[0], 0, 0, 0);
          acc1[1] = __builtin_amdgcn_mfma_f32_16x16x32_bf16(a1, b, acc1[1], 0, 0, 0);
        } else {       // layer 2, r-step rt, dout-half dh
          const int rt = (tt - 8) >> 1, dh = tt & 1;
          bfrag a0 = *(const bfrag*)&X[ln * XSTR + rt * 32 + kg * 8];
          bfrag a1 = *(const bfrag*)&X[(16 + ln) * XSTR + rt * 32 + kg * 8];
          acc2[0][dh] = __builtin_amdgcn_mfma_f32_16x16x32_bf16(a0, b, acc2[0][dh], 0, 0, 0);
          acc2[1][dh] = __builtin_amdgcn_mfma_f32_16x16x32_bf16(a1, b, acc2[1][dh], 0, 0, 0);
        }
      }
    }

    // ---- epilogue: partial plane (USE_WS) or atomic fallback
#pragma unroll
    for (int dh = 0; dh < 2; ++dh) {
      const int col = dh * 128 + c;
      const float b2v = (!USE_WS && rc == 0) ? b2[e * DIMC + col] : 0.f;
#pragma unroll
      for (int mt = 0; mt < 2; ++mt)
#pragma unroll
        for (int reg = 0; reg < 4; ++reg) {
          const int row = mt * 16 + kg * 4 + reg;
          if (row < m) {
            if (USE_WS) {
              prc[(size_t)sid[row] * DIMC + col] = acc2[mt][dh][reg];
            } else {
              atomicAdd(&out[(size_t)sid[row] * DIMC + col],
                        acc2[mt][dh][reg] + b2v);
            }
          }
        }
    }
  }

  // ==== fused reduce: last rc-block per expert sums 8 planes + b2 ====
  if (USE_WS) {
    __threadfence();  // release this block's partial stores
    if (t == 0) lastf = ((atomicAdd(&done[e], 1) & 7) == 7);
    __syncthreads();
    if (lastf) {
      __threadfence();  // acquire other blocks' partials
      for (int i = t; i < n * 64; i += 512) {
        const int s  = blist[i >> 6];
        const int c4 = i & 63;
        f32x4 acc = *(const f32x4*)(b2 + e * DIMC + c4 * 4);
#pragma unroll
        for (int r2 = 0; r2 < RCN; ++r2)
          acc += *(const f32x4*)(part + (size_t)r2 * NSLOT * DIMC +
                                 (size_t)s * DIMC + c4 * 4);
        *(f32x4*)(out + (size_t)s * DIMC + c4 * 4) = acc;
      }
    }
  }
}

extern "C" void kernel_launch(void* const* d_in, const int* in_sizes, int n_in,
                              void* d_out, int out_size, void* d_ws, size_t ws_size,
                              hipStream_t stream) {
  const float* slots   = (const float*)d_in[0];
  const float* w1      = (const float*)d_in[1];
  const float* b1      = (const float*)d_in[2];
  const float* w2      = (const float*)d_in[3];
  const float* b2      = (const float*)d_in[4];
  const int*   indices = (const int*)d_in[5];
  float* out = (float*)d_out;

  const size_t part_bytes = (size_t)RCN * NSLOT * DIMC * sizeof(float);  // 8 MB
  if (ws_size >= part_bytes + 256) {
    float* part = (float*)d_ws;
    int*   done = (int*)((char*)d_ws + part_bytes);
    // no memsets: done uses the mod-8 invariant; out written exactly once.
    mlp_kernel<1><<<dim3(NE, RCN), 512, 0, stream>>>(slots, w1, b1, w2, b2,
                                                     indices, part, done, out);
  } else {
    hipMemsetAsync(d_out, 0, (size_t)out_size * sizeof(float), stream);
    mlp_kernel<0><<<dim3(NE, RCN), 512, 0, stream>>>(slots, w1, b1, w2, b2,
                                                     indices, nullptr, nullptr,
                                                     out);
  }
}